// Round 1
// baseline (2012.848 us; speedup 1.0000x reference)
//
#include <hip/hip_runtime.h>
#include <math.h>

static constexpr int Bsz  = 16384;
static constexpr int Cdim = 1024;
static constexpr int Kdim = 128;
static constexpr int Vdim = 256;
static constexpr int Ssl  = 6;
static constexpr int HMd  = 512;
static constexpr int GOUTd= 1536;   // 4*384 gate hidden, column-fused
static constexpr int GDIM = 1669;
static constexpr int GPAD = 1696;   // 53*32
static constexpr int Mdim = 1024;

__device__ __forceinline__ float sigm(float x){ return 1.0f/(1.0f+expf(-x)); }
__device__ __forceinline__ float gelu(float x){ return 0.5f*x*(1.0f+erff(x*0.70710678118654752440f)); }

// ---- Wg1 (4,1669,384) -> Wg1t (1696, 1536) with zero pad rows >=1669 ----
__global__ __launch_bounds__(256) void k_transpose_wg1(const float* __restrict__ Wg1,
                                                       float* __restrict__ Wg1t){
    int idx = blockIdx.x*256 + threadIdx.x;
    if (idx >= GPAD*GOUTd) return;
    int f = idx / GOUTd, c = idx - f*GOUTd;
    int g = c / 384, h = c - g*384;
    Wg1t[idx] = (f < GDIM) ? Wg1[((size_t)g*GDIM + f)*384 + h] : 0.0f;
}

// ---- generic f32 GEMM: C[M,N] = act(A[M,K] @ W[K,N] + bias) ----
// BM=BN=64, BK=32, 256 threads, 4x4 micro-tile. M%64==0, N%64==0, K%32==0.
template<int ACT>
__global__ __launch_bounds__(256) void k_gemm(const float* __restrict__ A,
                                              const float* __restrict__ W,
                                              const float* __restrict__ bias,
                                              float* __restrict__ C,
                                              int M, int N, int K){
    __shared__ float As[32][68];   // [k][m], padded
    __shared__ float Ws[32][64];   // [k][n]
    int t  = threadIdx.x;
    int tx = t & 15, ty = t >> 4;
    size_t row0 = (size_t)blockIdx.y * 64;
    int col0 = blockIdx.x * 64;
    float acc[4][4] = {};
    int ra = t >> 3;          // 0..31
    int ca = (t & 7) << 2;    // 0,4,..,28
    int rw = t >> 4;          // 0..15
    int cw = (t & 15) << 2;   // 0,4,..,60

    for (int k0 = 0; k0 < K; k0 += 32){
        float4 a0 = *(const float4*)(A + (row0 + ra)*K + k0 + ca);
        float4 a1 = *(const float4*)(A + (row0 + ra + 32)*K + k0 + ca);
        float4 w0 = *(const float4*)(W + (size_t)(k0 + rw)*N + col0 + cw);
        float4 w1 = *(const float4*)(W + (size_t)(k0 + rw + 16)*N + col0 + cw);
        As[ca+0][ra] = a0.x; As[ca+1][ra] = a0.y; As[ca+2][ra] = a0.z; As[ca+3][ra] = a0.w;
        As[ca+0][ra+32] = a1.x; As[ca+1][ra+32] = a1.y; As[ca+2][ra+32] = a1.z; As[ca+3][ra+32] = a1.w;
        *(float4*)&Ws[rw][cw]    = w0;
        *(float4*)&Ws[rw+16][cw] = w1;
        __syncthreads();
        #pragma unroll
        for (int kk = 0; kk < 32; ++kk){
            float4 av = *(const float4*)&As[kk][ty*4];
            float4 wv = *(const float4*)&Ws[kk][tx*4];
            float a4[4] = {av.x, av.y, av.z, av.w};
            float w4[4] = {wv.x, wv.y, wv.z, wv.w};
            #pragma unroll
            for (int i=0;i<4;i++)
                #pragma unroll
                for (int j=0;j<4;j++)
                    acc[i][j] = fmaf(a4[i], w4[j], acc[i][j]);
        }
        __syncthreads();
    }
    #pragma unroll
    for (int i=0;i<4;i++){
        size_t r = row0 + ty*4 + i;
        #pragma unroll
        for (int j=0;j<4;j++){
            int c = col0 + tx*4 + j;
            float v = acc[i][j] + bias[c];
            if (ACT == 1) v = gelu(v);
            C[r*N + c] = v;
        }
    }
}

// ---- in-place l2 normalize rows of 128 ----
__global__ __launch_bounds__(256) void k_l2norm(float* __restrict__ x){
    int w = (blockIdx.x<<2) + (threadIdx.x>>6);
    int lane = threadIdx.x & 63;
    float2* r = (float2*)(x + (size_t)w*128);
    float2 v = r[lane];
    float ss = v.x*v.x + v.y*v.y;
    #pragma unroll
    for (int o=32;o;o>>=1) ss += __shfl_xor(ss,o);
    float inv = 1.0f / fmaxf(sqrtf(ss), 1e-6f);
    v.x *= inv; v.y *= inv;
    r[lane] = v;
}

// ---- slot match + feats build (one wave per row) ----
__global__ __launch_bounds__(256) void k_feats(const float* __restrict__ ctx,
        const float* __restrict__ ledger, const float* __restrict__ keys,
        const float* __restrict__ values, const float* __restrict__ age,
        const float* __restrict__ alive,  const float* __restrict__ ckC,
        const float* __restrict__ cvC,    float* __restrict__ feats,
        int* __restrict__ bidx, int b0){
    int w = (blockIdx.x<<2) + (threadIdx.x>>6);
    int lane = threadIdx.x & 63;
    size_t b = (size_t)b0 + w;
    float2 cc = ((const float2*)(ckC + (size_t)w*128))[lane];
    float best = -1e30f; int bi = 0; int anylive = 0;
    #pragma unroll
    for (int s=0;s<6;s++){
        float a = alive[b*6+s];
        float2 k2 = ((const float2*)(keys + (b*6+s)*128))[lane];
        float ss = k2.x*k2.x + k2.y*k2.y;
        float dt = cc.x*k2.x + cc.y*k2.y;
        #pragma unroll
        for (int o=32;o;o>>=1){ ss += __shfl_xor(ss,o); dt += __shfl_xor(dt,o); }
        float sc;
        if (a > 0.0f){ sc = dt / fmaxf(sqrtf(ss), 1e-6f); anylive = 1; }
        else sc = -1e4f;
        if (sc > best){ best = sc; bi = s; }   // strict > : first-max, matches jnp.argmax
    }
    float best_score = anylive ? best : 0.0f;
    int bis = anylive ? bi : 0;
    float4 mv = ((const float4*)(values + (b*6+bis)*256))[lane];
    float mage = age[b*6+bis];
    float cad = sigm((mage - 8.0f)*0.125f);
    float* f = feats + (size_t)w*GPAD;
    const float4* cr = (const float4*)(ctx + b*1024);
    float4* f4 = (float4*)f;
    #pragma unroll
    for (int i=0;i<4;i++) f4[lane + 64*i] = cr[lane + 64*i];
    ((float2*)(f+1024))[lane] = cc;
    ((float4*)(f+1152))[lane] = ((const float4*)(cvC + (size_t)w*256))[lane];
    ((float4*)(f+1408))[lane] = mv;
    if (lane == 0){
        f[1664] = best_score;
        f[1665] = cad;
        f[1666] = 1.0f - best_score;
        f[1667] = ledger[b*2];
        f[1668] = ledger[b*2+1];
        bidx[w] = bis;
    }
    if (lane < 27) f[1669+lane] = 0.0f;
}

// ---- gate head: probs[b,g] = sigmoid(dot(Hg[b, g*384:], Wg2[g]) + bg2[g]) ----
__global__ __launch_bounds__(256) void k_gate_head(const float* __restrict__ Hg,
        const float* __restrict__ Wg2, const float* __restrict__ bg2,
        float* __restrict__ probs){
    int w = (blockIdx.x<<2) + (threadIdx.x>>6);
    int lane = threadIdx.x & 63;
    const float* hr = Hg + (size_t)w*GOUTd;
    #pragma unroll
    for (int g=0; g<4; ++g){
        float acc = 0.f;
        #pragma unroll
        for (int i=0;i<6;i++){
            int idx = g*384 + i*64 + lane;
            acc += hr[idx] * Wg2[idx];
        }
        #pragma unroll
        for (int o=32;o;o>>=1) acc += __shfl_xor(acc,o);
        if (lane == 0) probs[w*4+g] = sigm(acc + bg2[g]);
    }
}

// ---- gates, spawn select, scatter update, summary (one wave per row) ----
__global__ __launch_bounds__(256) void k_update(const float* __restrict__ keys,
        const float* __restrict__ values, const float* __restrict__ conf,
        const float* __restrict__ age,    const float* __restrict__ alive,
        const float* __restrict__ ckC,    const float* __restrict__ cvC,
        const float* __restrict__ probs,  const int* __restrict__ bidx,
        float* __restrict__ o_keys, float* __restrict__ o_vals,
        float* __restrict__ o_conf, float* __restrict__ o_age,
        float* __restrict__ o_aliv, float* __restrict__ o_sum, int b0){
    int w = (blockIdx.x<<2) + (threadIdx.x>>6);
    int lane = threadIdx.x & 63;
    size_t b = (size_t)b0 + w;
    float rp = probs[w*4+0], sp = probs[w*4+1], tp = probs[w*4+3];
    float al[6], cf[6], ag[6];
    float hl = 0.f;
    #pragma unroll
    for (int s=0;s<6;s++){
        al[s]=alive[b*6+s]; cf[s]=conf[b*6+s]; ag[s]=age[b*6+s];
        hl = fmaxf(hl, al[s]);
    }
    float rr = hl * sigm((rp-0.55f)*4.0f);
    float sr = sigm((sp-0.60f)*4.0f);
    float den = 1.0f + rr + sr;
    float refresh = rr/den, spawn = sr/den;
    float retire = sigm((tp-0.15f)*4.0f);
    int bi = bidx[w];
    int ic = -1;
    #pragma unroll
    for (int s=5;s>=0;s--) if (al[s] < 0.5f) ic = s;   // first inactive
    int si;
    if (ic >= 0) si = ic;
    else {
        float bu = 1e30f; int am = 0;
        #pragma unroll
        for (int s=0;s<6;s++){
            float u = (s == bi) ? 1e4f : (cf[s] - 0.01f*ag[s]);
            if (u < bu){ bu = u; am = s; }             // strict < : first-min
        }
        si = am;
    }
    float2 cc  = ((const float2*)(ckC + (size_t)w*128))[lane];
    float4 cvv = ((const float4*)(cvC + (size_t)w*256))[lane];
    float s0=0,s1=0,s2=0,s3=0, wsum=0;
    #pragma unroll
    for (int s=0;s<6;s++){
        float wr = refresh*(s==bi ? 1.0f:0.0f) + spawn*(s==si ? 1.0f:0.0f);
        wr = fminf(wr, 1.0f);
        float rs = (s==bi) ? retire : 0.0f;
        float om = 1.0f - wr;
        float2 k2 = ((const float2*)(keys + (b*6+s)*128))[lane];
        float2 kn; kn.x = k2.x*om + wr*cc.x; kn.y = k2.y*om + wr*cc.y;
        ((float2*)(o_keys + (b*6+s)*128))[lane] = kn;
        float4 vv = ((const float4*)(values + (b*6+s)*256))[lane];
        float4 vn;
        vn.x = vv.x*om + wr*cvv.x; vn.y = vv.y*om + wr*cvv.y;
        vn.z = vv.z*om + wr*cvv.z; vn.w = vv.w*om + wr*cvv.w;
        ((float4*)(o_vals + (b*6+s)*256))[lane] = vn;
        float cn  = (cf[s]*0.995f*om + wr) * (1.0f - rs);
        float an  = fminf(fmaxf(al[s]*(1.0f - rs) + wr, 0.0f), 1.0f);
        float agn = (ag[s] + al[s]) * om;
        float wgt = an * cn;
        wsum += wgt;
        s0 += vn.x*wgt; s1 += vn.y*wgt; s2 += vn.z*wgt; s3 += vn.w*wgt;
        if (lane == s){ o_conf[b*6+s] = cn; o_age[b*6+s] = agn; o_aliv[b*6+s] = an; }
    }
    float inv = 1.0f/(wsum + 1e-6f);
    float4 sm; sm.x = s0*inv; sm.y = s1*inv; sm.z = s2*inv; sm.w = s3*inv;
    ((float4*)(o_sum + b*256))[lane] = sm;
}

// ---- layernorm + promote (one 256-thread block per row) ----
__global__ __launch_bounds__(256) void k_ln(const float* __restrict__ z,
        const float* __restrict__ probs, const float* __restrict__ g_ln,
        const float* __restrict__ b_ln,  float* __restrict__ o_prom, int b0){
    int w = blockIdx.x; int t = threadIdx.x;
    int lane = t & 63, wid = t >> 6;
    float4 v = ((const float4*)(z + (size_t)w*1024))[t];
    float s = v.x+v.y+v.z+v.w;
    #pragma unroll
    for (int o=32;o;o>>=1) s += __shfl_xor(s,o);
    __shared__ float red[4];
    if (lane==0) red[wid] = s;
    __syncthreads();
    float mu = (red[0]+red[1]+red[2]+red[3]) * (1.0f/1024.0f);
    float d0=v.x-mu, d1=v.y-mu, d2=v.z-mu, d3=v.w-mu;
    float ss = d0*d0+d1*d1+d2*d2+d3*d3;
    #pragma unroll
    for (int o=32;o;o>>=1) ss += __shfl_xor(ss,o);
    __syncthreads();
    if (lane==0) red[wid] = ss;
    __syncthreads();
    float var = (red[0]+red[1]+red[2]+red[3]) * (1.0f/1024.0f);
    float rstd = 1.0f / sqrtf(var + 1e-5f);
    float pm = sigm((probs[w*4+2]-0.50f)*4.0f);
    float4 g  = ((const float4*)g_ln)[t];
    float4 bb = ((const float4*)b_ln)[t];
    float4 o;
    o.x = pm*(d0*rstd*g.x + bb.x);
    o.y = pm*(d1*rstd*g.y + bb.y);
    o.z = pm*(d2*rstd*g.z + bb.z);
    o.w = pm*(d3*rstd*g.w + bb.w);
    ((float4*)(o_prom + ((size_t)b0 + w)*1024))[t] = o;
}

extern "C" void kernel_launch(void* const* d_in, const int* in_sizes, int n_in,
                              void* d_out, int out_size, void* d_ws, size_t ws_size,
                              hipStream_t stream){
    const float* ctx    = (const float*)d_in[0];
    const float* ledger = (const float*)d_in[1];
    const float* keys   = (const float*)d_in[2];
    const float* values = (const float*)d_in[3];
    const float* conf   = (const float*)d_in[4];
    const float* age    = (const float*)d_in[5];
    const float* alive  = (const float*)d_in[6];
    const float* Wk1 = (const float*)d_in[7];  const float* bk1 = (const float*)d_in[8];
    const float* Wk2 = (const float*)d_in[9];  const float* bk2 = (const float*)d_in[10];
    const float* Wv1 = (const float*)d_in[11]; const float* bv1 = (const float*)d_in[12];
    const float* Wv2 = (const float*)d_in[13]; const float* bv2 = (const float*)d_in[14];
    const float* Wg1 = (const float*)d_in[15]; const float* bg1 = (const float*)d_in[16];
    const float* Wg2 = (const float*)d_in[17]; const float* bg2 = (const float*)d_in[18];
    const float* Wsum= (const float*)d_in[19]; const float* bsum= (const float*)d_in[20];
    const float* g_ln= (const float*)d_in[21]; const float* b_ln= (const float*)d_in[22];

    float* out   = (float*)d_out;
    float* o_prom= out;
    float* o_sum = o_prom + (size_t)Bsz*Mdim;
    float* o_keys= o_sum  + (size_t)Bsz*Vdim;
    float* o_vals= o_keys + (size_t)Bsz*Ssl*Kdim;
    float* o_conf= o_vals + (size_t)Bsz*Ssl*Vdim;
    float* o_age = o_conf + (size_t)Bsz*Ssl;
    float* o_aliv= o_age  + (size_t)Bsz*Ssl;

    float* ws = (float*)d_ws;
    const size_t wg1t_f = (size_t)GPAD*GOUTd;
    // pick largest chunk CB that fits workspace
    int CB = 16384;
    while (CB > 64){
        size_t need_f = wg1t_f + (size_t)CB*(HMd + Kdim + Vdim + GPAD + GOUTd + 4 + 1);
        if (need_f*4 <= ws_size) break;
        CB >>= 1;
    }
    float* Wg1t   = ws;
    float* Hc     = Wg1t  + wg1t_f;
    float* ckc    = Hc    + (size_t)CB*HMd;
    float* cvc    = ckc   + (size_t)CB*Kdim;
    float* featsC = cvc   + (size_t)CB*Vdim;     // also reused as z chunk (CB*1024 <= CB*1696)
    float* HgC    = featsC+ (size_t)CB*GPAD;
    float* probsC = HgC   + (size_t)CB*GOUTd;
    int*   bidxC  = (int*)(probsC + (size_t)CB*4);

    dim3 blk(256);
    k_transpose_wg1<<<(GPAD*GOUTd + 255)/256, blk, 0, stream>>>(Wg1, Wg1t);

    for (int b0 = 0; b0 < Bsz; b0 += CB){
        const float* ctxc = ctx + (size_t)b0*Cdim;
        // key path (f32 to preserve argmax semantics)
        k_gemm<1><<<dim3(HMd/64,  CB/64), blk, 0, stream>>>(ctxc, Wk1, bk1, Hc,  CB, HMd,  Cdim);
        k_gemm<0><<<dim3(Kdim/64, CB/64), blk, 0, stream>>>(Hc,   Wk2, bk2, ckc, CB, Kdim, HMd);
        k_l2norm<<<CB/4, blk, 0, stream>>>(ckc);
        // value path
        k_gemm<1><<<dim3(HMd/64,  CB/64), blk, 0, stream>>>(ctxc, Wv1, bv1, Hc,  CB, HMd,  Cdim);
        k_gemm<0><<<dim3(Vdim/64, CB/64), blk, 0, stream>>>(Hc,   Wv2, bv2, cvc, CB, Vdim, HMd);
        // slot match + feats
        k_feats<<<CB/4, blk, 0, stream>>>(ctx, ledger, keys, values, age, alive,
                                          ckc, cvc, featsC, bidxC, b0);
        // gate MLP
        k_gemm<1><<<dim3(GOUTd/64, CB/64), blk, 0, stream>>>(featsC, Wg1t, bg1, HgC, CB, GOUTd, GPAD);
        k_gate_head<<<CB/4, blk, 0, stream>>>(HgC, Wg2, bg2, probsC);
        // scatter update + summary
        k_update<<<CB/4, blk, 0, stream>>>(keys, values, conf, age, alive, ckc, cvc,
                                           probsC, bidxC, o_keys, o_vals, o_conf,
                                           o_age, o_aliv, o_sum, b0);
        // summary projection + layernorm + promote
        k_gemm<0><<<dim3(Mdim/64, CB/64), blk, 0, stream>>>(o_sum + (size_t)b0*Vdim,
                                                            Wsum, bsum, featsC, CB, Mdim, Vdim);
        k_ln<<<CB, blk, 0, stream>>>(featsC, probsC, g_ln, b_ln, o_prom, b0);
    }
}

// Round 2
// 652.621 us; speedup vs baseline: 3.0843x; 3.0843x over previous
//
#include <hip/hip_runtime.h>
#include <math.h>

static constexpr int Bsz  = 16384;
static constexpr int Cdim = 1024;
static constexpr int Kdim = 128;
static constexpr int Vdim = 256;
static constexpr int Ssl  = 6;
static constexpr int HMd  = 512;
static constexpr int GOUTd= 1536;   // 4*384 gate hidden, column-fused
static constexpr int GDIM = 1669;
static constexpr int GPAD = 1728;   // 27*64, for BK=64 MFMA
static constexpr int Mdim = 1024;

typedef __attribute__((ext_vector_type(8))) short short8;
typedef __attribute__((ext_vector_type(4))) float f32x4;

__device__ __forceinline__ float sigm(float x){ return 1.0f/(1.0f+expf(-x)); }
__device__ __forceinline__ float gelu(float x){ return 0.5f*x*(1.0f+erff(x*0.70710678118654752440f)); }
__device__ __forceinline__ ushort f2b(float f){
    unsigned u = __builtin_bit_cast(unsigned, f);
    unsigned r = (u + 0x7fffu + ((u>>16)&1u)) >> 16;
    return (ushort)r;
}
__device__ __forceinline__ float b2f(ushort b){
    unsigned u = ((unsigned)b) << 16;
    return __builtin_bit_cast(float, u);
}

// ============================ prep kernels (run each launch) ============================

// f32 [K,N] -> bf16 [N,K] tiled transpose. K,N multiples of 64.
__global__ __launch_bounds__(256) void k_wt(const float* __restrict__ W,
                                            ushort* __restrict__ Wt, int K, int N){
    __shared__ float tile[64][65];
    int n0 = blockIdx.x*64, k0 = blockIdx.y*64;
    int tx = threadIdx.x & 63, ty = threadIdx.x >> 6;
    #pragma unroll
    for (int i=0;i<64;i+=4)
        tile[ty+i][tx] = W[(size_t)(k0+ty+i)*N + n0 + tx];
    __syncthreads();
    #pragma unroll
    for (int i=0;i<64;i+=4)
        Wt[(size_t)(n0+ty+i)*K + k0 + tx] = f2b(tile[tx][ty+i]);
}

// Wg1 (4,1669,384) -> bf16 [1536, 1728] row = g*384+h, col = f (zero pad f>=1669)
__global__ __launch_bounds__(256) void k_wg1t(const float* __restrict__ Wg1,
                                              ushort* __restrict__ Wt){
    __shared__ float tile[64][65];
    int g = blockIdx.z;
    int h0 = blockIdx.x*64, f0 = blockIdx.y*64;
    int tx = threadIdx.x & 63, ty = threadIdx.x >> 6;
    #pragma unroll
    for (int i=0;i<64;i+=4){
        int f = f0+ty+i;
        tile[ty+i][tx] = (f < GDIM) ? Wg1[((size_t)g*GDIM+f)*384 + h0+tx] : 0.0f;
    }
    __syncthreads();
    #pragma unroll
    for (int i=0;i<64;i+=4)
        Wt[((size_t)(g*384 + h0+ty+i))*GPAD + f0+tx] = f2b(tile[tx][ty+i]);
}

// f32 -> bf16 vectorized (n multiple of 4)
__global__ __launch_bounds__(256) void k_cvt(const float* __restrict__ x,
                                             ushort* __restrict__ y, size_t n4){
    size_t i = (size_t)blockIdx.x*256 + threadIdx.x;
    if (i >= n4) return;
    float4 v = ((const float4*)x)[i];
    ushort4 o = { f2b(v.x), f2b(v.y), f2b(v.z), f2b(v.w) };
    ((ushort4*)y)[i] = o;
}

// ============================ f32 GEMM (key path only) ============================
template<int ACT>
__global__ __launch_bounds__(256) void k_gemm(const float* __restrict__ A,
                                              const float* __restrict__ W,
                                              const float* __restrict__ bias,
                                              float* __restrict__ C,
                                              int M, int N, int K){
    __shared__ float As[32][68];
    __shared__ float Ws[32][64];
    int t  = threadIdx.x;
    int tx = t & 15, ty = t >> 4;
    size_t row0 = (size_t)blockIdx.y * 64;
    int col0 = blockIdx.x * 64;
    float acc[4][4] = {};
    int ra = t >> 3;
    int ca = (t & 7) << 2;
    int rw = t >> 4;
    int cw = (t & 15) << 2;
    for (int k0 = 0; k0 < K; k0 += 32){
        float4 a0 = *(const float4*)(A + (row0 + ra)*K + k0 + ca);
        float4 a1 = *(const float4*)(A + (row0 + ra + 32)*K + k0 + ca);
        float4 w0 = *(const float4*)(W + (size_t)(k0 + rw)*N + col0 + cw);
        float4 w1 = *(const float4*)(W + (size_t)(k0 + rw + 16)*N + col0 + cw);
        As[ca+0][ra] = a0.x; As[ca+1][ra] = a0.y; As[ca+2][ra] = a0.z; As[ca+3][ra] = a0.w;
        As[ca+0][ra+32] = a1.x; As[ca+1][ra+32] = a1.y; As[ca+2][ra+32] = a1.z; As[ca+3][ra+32] = a1.w;
        *(float4*)&Ws[rw][cw]    = w0;
        *(float4*)&Ws[rw+16][cw] = w1;
        __syncthreads();
        #pragma unroll
        for (int kk = 0; kk < 32; ++kk){
            float4 av = *(const float4*)&As[kk][ty*4];
            float4 wv = *(const float4*)&Ws[kk][tx*4];
            float a4[4] = {av.x, av.y, av.z, av.w};
            float w4[4] = {wv.x, wv.y, wv.z, wv.w};
            #pragma unroll
            for (int i=0;i<4;i++)
                #pragma unroll
                for (int j=0;j<4;j++)
                    acc[i][j] = fmaf(a4[i], w4[j], acc[i][j]);
        }
        __syncthreads();
    }
    #pragma unroll
    for (int i=0;i<4;i++){
        size_t r = row0 + ty*4 + i;
        #pragma unroll
        for (int j=0;j<4;j++){
            int c = col0 + tx*4 + j;
            float v = acc[i][j] + bias[c];
            if (ACT == 1) v = gelu(v);
            C[r*N + c] = v;
        }
    }
}

// ============================ bf16 MFMA GEMM ============================
// A [M,K] bf16 row-major, Bt [N,K] bf16 row-major (i.e. B transposed).
// C[M,N] = act(A@B + bias). M%128==0, N%128==0, K%64==0.
// 128x128 tile, BK=64, 4 waves (2x2), global_load_lds w16, XOR-swizzled LDS.
__device__ __forceinline__ void gload_lds16(const void* g, void* l){
    typedef __attribute__((address_space(1))) const unsigned gu32;
    typedef __attribute__((address_space(3))) unsigned lu32;
    __builtin_amdgcn_global_load_lds((gu32*)(unsigned long long)g,
                                     (lu32*)(unsigned)(unsigned long long)l,
                                     16, 0, 0);
}

template<int ACT, int OUTBF>
__global__ __launch_bounds__(256) void k_mfma_gemm(const ushort* __restrict__ A,
                                                   const ushort* __restrict__ Bt,
                                                   const float* __restrict__ bias,
                                                   void* __restrict__ Cout,
                                                   int M, int N, int K){
    __shared__ alignas(16) ushort lds[16384];   // As[128][64] then Bs[128][64]
    ushort* As = lds;
    ushort* Bs = lds + 8192;
    int t = threadIdx.x;
    int l = t & 63, w = t >> 6;
    int wm = w >> 1, wn = w & 1;
    size_t row0 = (size_t)blockIdx.y * 128;
    int col0 = blockIdx.x * 128;
    f32x4 acc[4][4] = {};
    int lrow = l >> 3;                 // 0..7 row-within-chunk
    int lc8  = (l & 7) ^ lrow;         // swizzled source 8-elem chunk

    for (int k0 = 0; k0 < K; k0 += 64){
        #pragma unroll
        for (int i = 0; i < 4; ++i){
            int ch = w*4 + i;                    // 0..15
            int r  = ch*8 + lrow;                // 0..127
            gload_lds16(A  + (row0 + r)*(size_t)K + k0 + lc8*8, As + ch*512);
            gload_lds16(Bt + (size_t)(col0 + r)*K + k0 + lc8*8, Bs + ch*512);
        }
        __syncthreads();
        #pragma unroll
        for (int kk = 0; kk < 2; ++kk){
            short8 af[4], bfr[4];
            int j8 = kk*4 + (l >> 4);
            #pragma unroll
            for (int m = 0; m < 4; ++m){
                int row = wm*64 + m*16 + (l & 15);
                int c16 = j8 ^ (row & 7);
                af[m] = *(const short8*)(As + row*64 + c16*8);
            }
            #pragma unroll
            for (int n = 0; n < 4; ++n){
                int rowb = wn*64 + n*16 + (l & 15);
                int c16 = j8 ^ (rowb & 7);
                bfr[n] = *(const short8*)(Bs + rowb*64 + c16*8);
            }
            #pragma unroll
            for (int m = 0; m < 4; ++m)
                #pragma unroll
                for (int n = 0; n < 4; ++n)
                    acc[m][n] = __builtin_amdgcn_mfma_f32_16x16x32_bf16(af[m], bfr[n], acc[m][n], 0, 0, 0);
        }
        __syncthreads();
    }
    // epilogue: C/D layout col = l&15, row = (l>>4)*4 + i  (m89-verified)
    int q = l >> 4, cf = l & 15;
    #pragma unroll
    for (int m = 0; m < 4; ++m){
        #pragma unroll
        for (int n = 0; n < 4; ++n){
            int col = col0 + wn*64 + n*16 + cf;
            float bv = bias[col];
            #pragma unroll
            for (int i = 0; i < 4; ++i){
                size_t r = row0 + wm*64 + m*16 + q*4 + i;
                float v = acc[m][n][i] + bv;
                if (ACT == 1) v = gelu(v);
                if (OUTBF) ((ushort*)Cout)[r*N + col] = f2b(v);
                else       ((float*) Cout)[r*N + col] = v;
            }
        }
    }
}

// ---- in-place l2 normalize rows of 128 ----
__global__ __launch_bounds__(256) void k_l2norm(float* __restrict__ x){
    int w = (blockIdx.x<<2) + (threadIdx.x>>6);
    int lane = threadIdx.x & 63;
    float2* r = (float2*)(x + (size_t)w*128);
    float2 v = r[lane];
    float ss = v.x*v.x + v.y*v.y;
    #pragma unroll
    for (int o=32;o;o>>=1) ss += __shfl_xor(ss,o);
    float inv = 1.0f / fmaxf(sqrtf(ss), 1e-6f);
    v.x *= inv; v.y *= inv;
    r[lane] = v;
}

// ---- slot match + feats build (bf16 feats out) ----
__global__ __launch_bounds__(256) void k_feats(const float* __restrict__ ctx,
        const float* __restrict__ ledger, const float* __restrict__ keys,
        const float* __restrict__ values, const float* __restrict__ age,
        const float* __restrict__ alive,  const float* __restrict__ ckC,
        const float* __restrict__ cvC,    ushort* __restrict__ feats,
        int* __restrict__ bidx, int b0){
    int w = (blockIdx.x<<2) + (threadIdx.x>>6);
    int lane = threadIdx.x & 63;
    size_t b = (size_t)b0 + w;
    float2 cc = ((const float2*)(ckC + (size_t)w*128))[lane];
    float best = -1e30f; int bi = 0; int anylive = 0;
    #pragma unroll
    for (int s=0;s<6;s++){
        float a = alive[b*6+s];
        float2 k2 = ((const float2*)(keys + (b*6+s)*128))[lane];
        float ss = k2.x*k2.x + k2.y*k2.y;
        float dt = cc.x*k2.x + cc.y*k2.y;
        #pragma unroll
        for (int o=32;o;o>>=1){ ss += __shfl_xor(ss,o); dt += __shfl_xor(dt,o); }
        float sc;
        if (a > 0.0f){ sc = dt / fmaxf(sqrtf(ss), 1e-6f); anylive = 1; }
        else sc = -1e4f;
        if (sc > best){ best = sc; bi = s; }
    }
    float best_score = anylive ? best : 0.0f;
    int bis = anylive ? bi : 0;
    float4 mv = ((const float4*)(values + (b*6+bis)*256))[lane];
    float mage = age[b*6+bis];
    float cad = sigm((mage - 8.0f)*0.125f);
    ushort* f = feats + (size_t)w*GPAD;
    const float4* cr = (const float4*)(ctx + b*1024);
    #pragma unroll
    for (int i=0;i<4;i++){
        float4 v = cr[lane + 64*i];
        ushort4 o = { f2b(v.x), f2b(v.y), f2b(v.z), f2b(v.w) };
        ((ushort4*)f)[lane + 64*i] = o;
    }
    { ushort2 o = { f2b(cc.x), f2b(cc.y) };
      ((ushort2*)(f+1024))[lane] = o; }
    { float4 v = ((const float4*)(cvC + (size_t)w*256))[lane];
      ushort4 o = { f2b(v.x), f2b(v.y), f2b(v.z), f2b(v.w) };
      ((ushort4*)(f+1152))[lane] = o; }
    { ushort4 o = { f2b(mv.x), f2b(mv.y), f2b(mv.z), f2b(mv.w) };
      ((ushort4*)(f+1408))[lane] = o; }
    if (lane == 0){
        f[1664] = f2b(best_score);
        f[1665] = f2b(cad);
        f[1666] = f2b(1.0f - best_score);
        f[1667] = f2b(ledger[b*2]);
        f[1668] = f2b(ledger[b*2+1]);
        bidx[w] = bis;
    }
    if (lane < GPAD - 1669) f[1669+lane] = 0;
}

// ---- gate head (bf16 Hg in) ----
__global__ __launch_bounds__(256) void k_gate_head(const ushort* __restrict__ Hg,
        const float* __restrict__ Wg2, const float* __restrict__ bg2,
        float* __restrict__ probs){
    int w = (blockIdx.x<<2) + (threadIdx.x>>6);
    int lane = threadIdx.x & 63;
    const ushort* hr = Hg + (size_t)w*GOUTd;
    #pragma unroll
    for (int g=0; g<4; ++g){
        float acc = 0.f;
        #pragma unroll
        for (int i=0;i<6;i++){
            int idx = g*384 + i*64 + lane;
            acc += b2f(hr[idx]) * Wg2[idx];
        }
        #pragma unroll
        for (int o=32;o;o>>=1) acc += __shfl_xor(acc,o);
        if (lane == 0) probs[w*4+g] = sigm(acc + bg2[g]);
    }
}

// ---- gates, spawn select, scatter update, summary ----
__global__ __launch_bounds__(256) void k_update(const float* __restrict__ keys,
        const float* __restrict__ values, const float* __restrict__ conf,
        const float* __restrict__ age,    const float* __restrict__ alive,
        const float* __restrict__ ckC,    const float* __restrict__ cvC,
        const float* __restrict__ probs,  const int* __restrict__ bidx,
        float* __restrict__ o_keys, float* __restrict__ o_vals,
        float* __restrict__ o_conf, float* __restrict__ o_age,
        float* __restrict__ o_aliv, float* __restrict__ o_sum,
        ushort* __restrict__ o_sumb, int b0){
    int w = (blockIdx.x<<2) + (threadIdx.x>>6);
    int lane = threadIdx.x & 63;
    size_t b = (size_t)b0 + w;
    float rp = probs[w*4+0], sp = probs[w*4+1], tp = probs[w*4+3];
    float al[6], cf[6], ag[6];
    float hl = 0.f;
    #pragma unroll
    for (int s=0;s<6;s++){
        al[s]=alive[b*6+s]; cf[s]=conf[b*6+s]; ag[s]=age[b*6+s];
        hl = fmaxf(hl, al[s]);
    }
    float rr = hl * sigm((rp-0.55f)*4.0f);
    float sr = sigm((sp-0.60f)*4.0f);
    float den = 1.0f + rr + sr;
    float refresh = rr/den, spawn = sr/den;
    float retire = sigm((tp-0.15f)*4.0f);
    int bi = bidx[w];
    int ic = -1;
    #pragma unroll
    for (int s=5;s>=0;s--) if (al[s] < 0.5f) ic = s;
    int si;
    if (ic >= 0) si = ic;
    else {
        float bu = 1e30f; int am = 0;
        #pragma unroll
        for (int s=0;s<6;s++){
            float u = (s == bi) ? 1e4f : (cf[s] - 0.01f*ag[s]);
            if (u < bu){ bu = u; am = s; }
        }
        si = am;
    }
    float2 cc  = ((const float2*)(ckC + (size_t)w*128))[lane];
    float4 cvv = ((const float4*)(cvC + (size_t)w*256))[lane];
    float s0=0,s1=0,s2=0,s3=0, wsum=0;
    #pragma unroll
    for (int s=0;s<6;s++){
        float wr = refresh*(s==bi ? 1.0f:0.0f) + spawn*(s==si ? 1.0f:0.0f);
        wr = fminf(wr, 1.0f);
        float rs = (s==bi) ? retire : 0.0f;
        float om = 1.0f - wr;
        float2 k2 = ((const float2*)(keys + (b*6+s)*128))[lane];
        float2 kn; kn.x = k2.x*om + wr*cc.x; kn.y = k2.y*om + wr*cc.y;
        ((float2*)(o_keys + (b*6+s)*128))[lane] = kn;
        float4 vv = ((const float4*)(values + (b*6+s)*256))[lane];
        float4 vn;
        vn.x = vv.x*om + wr*cvv.x; vn.y = vv.y*om + wr*cvv.y;
        vn.z = vv.z*om + wr*cvv.z; vn.w = vv.w*om + wr*cvv.w;
        ((float4*)(o_vals + (b*6+s)*256))[lane] = vn;
        float cn  = (cf[s]*0.995f*om + wr) * (1.0f - rs);
        float an  = fminf(fmaxf(al[s]*(1.0f - rs) + wr, 0.0f), 1.0f);
        float agn = (ag[s] + al[s]) * om;
        float wgt = an * cn;
        wsum += wgt;
        s0 += vn.x*wgt; s1 += vn.y*wgt; s2 += vn.z*wgt; s3 += vn.w*wgt;
        if (lane == s){ o_conf[b*6+s] = cn; o_age[b*6+s] = agn; o_aliv[b*6+s] = an; }
    }
    float inv = 1.0f/(wsum + 1e-6f);
    float4 sm; sm.x = s0*inv; sm.y = s1*inv; sm.z = s2*inv; sm.w = s3*inv;
    ((float4*)(o_sum + b*256))[lane] = sm;
    ushort4 sb = { f2b(sm.x), f2b(sm.y), f2b(sm.z), f2b(sm.w) };
    ((ushort4*)(o_sumb + (size_t)w*256))[lane] = sb;
}

// ---- layernorm + promote ----
__global__ __launch_bounds__(256) void k_ln(const float* __restrict__ z,
        const float* __restrict__ probs, const float* __restrict__ g_ln,
        const float* __restrict__ b_ln,  float* __restrict__ o_prom, int b0){
    int w = blockIdx.x; int t = threadIdx.x;
    int lane = t & 63, wid = t >> 6;
    float4 v = ((const float4*)(z + (size_t)w*1024))[t];
    float s = v.x+v.y+v.z+v.w;
    #pragma unroll
    for (int o=32;o;o>>=1) s += __shfl_xor(s,o);
    __shared__ float red[4];
    if (lane==0) red[wid] = s;
    __syncthreads();
    float mu = (red[0]+red[1]+red[2]+red[3]) * (1.0f/1024.0f);
    float d0=v.x-mu, d1=v.y-mu, d2=v.z-mu, d3=v.w-mu;
    float ss = d0*d0+d1*d1+d2*d2+d3*d3;
    #pragma unroll
    for (int o=32;o;o>>=1) ss += __shfl_xor(ss,o);
    __syncthreads();
    if (lane==0) red[wid] = ss;
    __syncthreads();
    float var = (red[0]+red[1]+red[2]+red[3]) * (1.0f/1024.0f);
    float rstd = 1.0f / sqrtf(var + 1e-5f);
    float pm = sigm((probs[w*4+2]-0.50f)*4.0f);
    float4 g  = ((const float4*)g_ln)[t];
    float4 bb = ((const float4*)b_ln)[t];
    float4 o;
    o.x = pm*(d0*rstd*g.x + bb.x);
    o.y = pm*(d1*rstd*g.y + bb.y);
    o.z = pm*(d2*rstd*g.z + bb.z);
    o.w = pm*(d3*rstd*g.w + bb.w);
    ((float4*)(o_prom + ((size_t)b0 + w)*1024))[t] = o;
}

extern "C" void kernel_launch(void* const* d_in, const int* in_sizes, int n_in,
                              void* d_out, int out_size, void* d_ws, size_t ws_size,
                              hipStream_t stream){
    const float* ctx    = (const float*)d_in[0];
    const float* ledger = (const float*)d_in[1];
    const float* keys   = (const float*)d_in[2];
    const float* values = (const float*)d_in[3];
    const float* conf   = (const float*)d_in[4];
    const float* age    = (const float*)d_in[5];
    const float* alive  = (const float*)d_in[6];
    const float* Wk1 = (const float*)d_in[7];  const float* bk1 = (const float*)d_in[8];
    const float* Wk2 = (const float*)d_in[9];  const float* bk2 = (const float*)d_in[10];
    const float* Wv1 = (const float*)d_in[11]; const float* bv1 = (const float*)d_in[12];
    const float* Wv2 = (const float*)d_in[13]; const float* bv2 = (const float*)d_in[14];
    const float* Wg1 = (const float*)d_in[15]; const float* bg1 = (const float*)d_in[16];
    const float* Wg2 = (const float*)d_in[17]; const float* bg2 = (const float*)d_in[18];
    const float* Wsum= (const float*)d_in[19]; const float* bsum= (const float*)d_in[20];
    const float* g_ln= (const float*)d_in[21]; const float* b_ln= (const float*)d_in[22];

    float* out   = (float*)d_out;
    float* o_prom= out;
    float* o_sum = o_prom + (size_t)Bsz*Mdim;
    float* o_keys= o_sum  + (size_t)Bsz*Vdim;
    float* o_vals= o_keys + (size_t)Bsz*Ssl*Kdim;
    float* o_conf= o_vals + (size_t)Bsz*Ssl*Vdim;
    float* o_age = o_conf + (size_t)Bsz*Ssl;
    float* o_aliv= o_age  + (size_t)Bsz*Ssl;

    // ---------- workspace layout ----------
    char* p = (char*)d_ws;
    auto alloc = [&](size_t bytes)->char*{
        char* r = p; p += (bytes + 255) & ~(size_t)255; return r;
    };
    ushort* ctxb  = (ushort*)alloc((size_t)Bsz*Cdim*2);
    ushort* Wv1t  = (ushort*)alloc((size_t)HMd*Cdim*2);        // [512,1024]
    ushort* Wv2t  = (ushort*)alloc((size_t)Vdim*HMd*2);        // [256,512]
    ushort* Wg1tt = (ushort*)alloc((size_t)GOUTd*GPAD*2);      // [1536,1728]
    ushort* Wsumt = (ushort*)alloc((size_t)Mdim*Vdim*2);       // [1024,256]
    size_t fixed = (size_t)(p - (char*)d_ws);
    size_t per_row = 2048 + 512 + 1024 + 1024 + (size_t)GPAD*2 + (size_t)GOUTd*2 + 4096 + 512 + 16 + 4 + 64;
    int CB = 16384;
    while (CB > 128 && fixed + (size_t)CB*per_row + 8192 > ws_size) CB >>= 1;
    float*  Hc     = (float*) alloc((size_t)CB*HMd*4);     // key hidden f32
    float*  ckc    = (float*) alloc((size_t)CB*Kdim*4);
    ushort* Hb     = (ushort*)alloc((size_t)CB*HMd*2);     // value hidden bf16
    float*  cvc    = (float*) alloc((size_t)CB*Vdim*4);
    ushort* featsb = (ushort*)alloc((size_t)CB*GPAD*2);
    ushort* Hgb    = (ushort*)alloc((size_t)CB*GOUTd*2);
    float*  zbuf   = (float*) alloc((size_t)CB*Mdim*4);
    ushort* sumb   = (ushort*)alloc((size_t)CB*Vdim*2);
    float*  probsC = (float*) alloc((size_t)CB*4*4);
    int*    bidxC  = (int*)   alloc((size_t)CB*4);

    dim3 blk(256);
    // ---------- one-time prep (runs each launch; cheap, tiled) ----------
    k_cvt<<<(int)(((size_t)Bsz*Cdim/4 + 255)/256), blk, 0, stream>>>(ctx, ctxb, (size_t)Bsz*Cdim/4);
    k_wt<<<dim3(HMd/64,  Cdim/64), blk, 0, stream>>>(Wv1, Wv1t, Cdim, HMd);
    k_wt<<<dim3(Vdim/64, HMd/64),  blk, 0, stream>>>(Wv2, Wv2t, HMd, Vdim);
    k_wt<<<dim3(Mdim/64, Vdim/64), blk, 0, stream>>>(Wsum, Wsumt, Vdim, Mdim);
    k_wg1t<<<dim3(384/64, GPAD/64, 4), blk, 0, stream>>>(Wg1, Wg1tt);

    for (int b0 = 0; b0 < Bsz; b0 += CB){
        const float* ctxc = ctx + (size_t)b0*Cdim;
        // key path: f32 (argmax-exact, bit-identical to round 1)
        k_gemm<1><<<dim3(HMd/64,  CB/64), blk, 0, stream>>>(ctxc, Wk1, bk1, Hc,  CB, HMd,  Cdim);
        k_gemm<0><<<dim3(Kdim/64, CB/64), blk, 0, stream>>>(Hc,   Wk2, bk2, ckc, CB, Kdim, HMd);
        k_l2norm<<<CB/4, blk, 0, stream>>>(ckc);
        // value path: bf16 MFMA
        k_mfma_gemm<1,1><<<dim3(HMd/128,  CB/128), blk, 0, stream>>>(ctxb + (size_t)b0*Cdim, Wv1t, bv1, Hb,  CB, HMd,  Cdim);
        k_mfma_gemm<0,0><<<dim3(Vdim/128, CB/128), blk, 0, stream>>>(Hb, Wv2t, bv2, cvc, CB, Vdim, HMd);
        // slot match + feats (bf16)
        k_feats<<<CB/4, blk, 0, stream>>>(ctx, ledger, keys, values, age, alive,
                                          ckc, cvc, featsb, bidxC, b0);
        // gate MLP: bf16 MFMA
        k_mfma_gemm<1,1><<<dim3(GOUTd/128, CB/128), blk, 0, stream>>>(featsb, Wg1tt, bg1, Hgb, CB, GOUTd, GPAD);
        k_gate_head<<<CB/4, blk, 0, stream>>>(Hgb, Wg2, bg2, probsC);
        // scatter update + summary
        k_update<<<CB/4, blk, 0, stream>>>(keys, values, conf, age, alive, ckc, cvc,
                                           probsC, bidxC, o_keys, o_vals, o_conf,
                                           o_age, o_aliv, o_sum, sumb, b0);
        // summary projection: bf16 MFMA, then LN + promote
        k_mfma_gemm<0,0><<<dim3(Mdim/128, CB/128), blk, 0, stream>>>(sumb, Wsumt, bsum, zbuf, CB, Mdim, Vdim);
        k_ln<<<CB, blk, 0, stream>>>(zbuf, probsC, g_ln, b_ln, o_prom, b0);
    }
}